// Round 9
// baseline (319.826 us; speedup 1.0000x reference)
//
#include <hip/hip_runtime.h>
#include <hip/hip_bf16.h>

#define NC 80
#define NK 51
#define REG_MAX 16
#define MAX_DET 100
#define A_TOT 8400
#define BS 16

// out layout (float32): num[16] | boxes[16*100*4] | scores[16*100] | classes[16*100] | kpts[16*100*17*3]
#define OUT_NUM 0
#define OUT_BOX 16
#define OUT_SCORE (16 + 16*MAX_DET*4)
#define OUT_CLASS (OUT_SCORE + 16*MAX_DET)
#define OUT_KPT (OUT_CLASS + 16*MAX_DET)

static __device__ __forceinline__ unsigned long long mk_key(unsigned u, int a) {
    return ((unsigned long long)u << 32) | (unsigned)(0x7FFFFFFF - a);
}

// ---- per-level equal-work scores body ----
// 256 threads = 4 waves x 20 ocs. APT = anchors/thread (4/2/1 for C=128/256/512)
// so every block does C*64*APT*80 = 2.62M FMA -> uniform block runtime, no tail.
// Weights in LDS (broadcast ds_read_b128), features LDS [c][a].
template <int APT>
__device__ __forceinline__ void scores_level(
    const float* __restrict__ xb,   // x + b*C*A
    const float* __restrict__ w, const float* __restrict__ bias,
    int C, int A, int a_off, int a0, int b,
    float* __restrict__ fs, float* __restrict__ wsh,
    float* __restrict__ max_s, int* __restrict__ cls_id,
    int t, int lane, int wv)
{
    const int NA = APT * 64;         // anchors per block
    int oc0 = wv * 20;

    float acc[20][APT];
#pragma unroll
    for (int j = 0; j < 20; ++j) {
        float bv = bias[oc0 + j];
#pragma unroll
        for (int an = 0; an < APT; ++an) acc[j][an] = bv;
    }

    int nchunk = C >> 5;
    for (int kc = 0; kc < nchunk; ++kc) {
        __syncthreads();
        // stage features: 32 channels x NA anchors = 8*NA float4, 256 threads
#pragma unroll
        for (int i = 0; i < 2 * APT; ++i) {
            int idx = t + i * 256;
            int c = idx / (NA / 4);
            int q = (idx % (NA / 4)) * 4;
            int aa = a0 + q; if (aa > A - 4) aa = A - 4;   // clamp; masked at write
            float4 v = *(const float4*)(xb + (long)(kc * 32 + c) * A + aa);
            *(float4*)(&fs[c * NA + q]) = v;
        }
        // stage weights: 80 ocs x 32 channels (640 float4)
#pragma unroll
        for (int i = 0; i < 3; ++i) {
            int idx = t + i * 256;
            if (idx < 640) {
                int oc = idx >> 3;
                int q = (idx & 7) * 4;
                float4 v = *(const float4*)(w + oc * C + kc * 32 + q);
                *(float4*)(&wsh[oc * 32 + q]) = v;
            }
        }
        __syncthreads();

#pragma unroll 1
        for (int c4 = 0; c4 < 32; c4 += 4) {
            float fv[4][APT];
#pragma unroll
            for (int cc = 0; cc < 4; ++cc) {
                if constexpr (APT == 4) {
                    float4 f = *(const float4*)&fs[(c4 + cc) * NA + lane * 4];
                    fv[cc][0] = f.x; fv[cc][1] = f.y; fv[cc][2] = f.z; fv[cc][3] = f.w;
                } else if constexpr (APT == 2) {
                    float2 f = *(const float2*)&fs[(c4 + cc) * NA + lane * 2];
                    fv[cc][0] = f.x; fv[cc][1] = f.y;
                } else {
                    fv[cc][0] = fs[(c4 + cc) * NA + lane];
                }
            }
#pragma unroll
            for (int j = 0; j < 20; ++j) {
                float4 wj = *(const float4*)(&wsh[(oc0 + j) * 32 + c4]);  // broadcast
#pragma unroll
                for (int an = 0; an < APT; ++an) {
                    acc[j][an] = fmaf(wj.x, fv[0][an], acc[j][an]);
                    acc[j][an] = fmaf(wj.y, fv[1][an], acc[j][an]);
                    acc[j][an] = fmaf(wj.z, fv[2][an], acc[j][an]);
                    acc[j][an] = fmaf(wj.w, fv[3][an], acc[j][an]);
                }
            }
        }
    }

    // per-thread argmax over 20 ocs (first-max semantics)
    float m[APT]; int mi[APT];
#pragma unroll
    for (int an = 0; an < APT; ++an) { m[an] = acc[0][an]; mi[an] = 0; }
#pragma unroll
    for (int j = 1; j < 20; ++j) {
#pragma unroll
        for (int an = 0; an < APT; ++an)
            if (acc[j][an] > m[an]) { m[an] = acc[j][an]; mi[an] = j; }
    }

    __syncthreads();
    float* rm = fs;                   // [4][NA] reuse
    int*   ri = (int*)(fs + 4 * NA);  // [4][NA]
#pragma unroll
    for (int an = 0; an < APT; ++an) {
        rm[wv * NA + lane * APT + an] = m[an];
        ri[wv * NA + lane * APT + an] = mi[an] + oc0;
    }
    __syncthreads();

    if (t < NA) {
        float bm = rm[t]; int bi = ri[t];
#pragma unroll
        for (int v = 1; v < 4; ++v) {
            float om = rm[v * NA + t];
            if (om > bm) { bm = om; bi = ri[v * NA + t]; }  // ascending oc keeps first max
        }
        int ga = a0 + t;
        if (ga < A) {
            max_s[b * A_TOT + a_off + ga] = 1.0f / (1.0f + expf(-bm));
            cls_id[b * A_TOT + a_off + ga] = bi;
        }
    }
}

// -------- Kernel 1: fused, equal-work-per-block class scores --------
// Grid 720 = 112 (L2,64a) + 208 (L1,128a) + 400 (L0,256a); 3 blocks/CU
// (LDS 42KB*3=126<=160KB, VGPR cap ~170 > ~130 needed).
__global__ __launch_bounds__(256, 3) void scores_fused(
    const float* __restrict__ x0, const float* __restrict__ x1, const float* __restrict__ x2,
    const float* __restrict__ w0, const float* __restrict__ w1, const float* __restrict__ w2,
    const float* __restrict__ bias0, const float* __restrict__ bias1, const float* __restrict__ bias2,
    float* __restrict__ max_s,       // [BS][A_TOT]
    int* __restrict__ cls_id)        // [BS][A_TOT]
{
    __shared__ float fs[32 * 256];   // 32 KB max (L0); reused for argmax reduce
    __shared__ float wsh[80 * 32];   // 10 KB

    int bid = blockIdx.x;
    int t = threadIdx.x;
    int lane = t & 63;
    int wv = __builtin_amdgcn_readfirstlane(t >> 6);  // 0..3, wave-uniform

    if (bid < 112) {                 // L2: C=512, 7 tiles x 16 b, 64 anchors
        int b = bid / 7, tile = bid - b * 7;
        scores_level<1>(x2 + (long)b * 512 * 400, w2, bias2, 512, 400, 8000,
                        tile * 64, b, fs, wsh, max_s, cls_id, t, lane, wv);
    } else if (bid < 320) {          // L1: C=256, 13 tiles x 16 b, 128 anchors
        int r = bid - 112;
        int b = r / 13, tile = r - b * 13;
        scores_level<2>(x1 + (long)b * 256 * 1600, w1, bias1, 256, 1600, 6400,
                        tile * 128, b, fs, wsh, max_s, cls_id, t, lane, wv);
    } else {                         // L0: C=128, 25 tiles x 16 b, 256 anchors
        int r = bid - 320;
        int b = r / 25, tile = r - b * 25;
        scores_level<4>(x0 + (long)b * 128 * 6400, w0, bias0, 128, 6400, 0,
                        tile * 256, b, fs, wsh, max_s, cls_id, t, lane, wv);
    }
}

// -------- Kernel 2: exact top-100 per batch via radix select --------
__global__ __launch_bounds__(1024) void topk_kernel(
    const float* __restrict__ max_s, // [BS][A_TOT]
    const int* __restrict__ cls_id,  // [BS][A_TOT]
    float* __restrict__ out,
    int* __restrict__ top_idx)       // [BS][MAX_DET]
{
    int b = blockIdx.x;
    int t = threadIdx.x;
    int wv = t >> 6;

    __shared__ unsigned hist[16 * 256];
    __shared__ unsigned suffix[256];
    __shared__ int tieIdx[A_TOT];
    __shared__ unsigned long long highKeys[128];
    __shared__ unsigned long long finalKeys[128];
    __shared__ int wmin[16];
    __shared__ unsigned s_prefix;
    __shared__ int s_k, s_selD, s_nHigh, s_nTie, s_cnt, s_bcast;

    unsigned u[9];
    bool val[9];
#pragma unroll
    for (int i = 0; i < 9; ++i) {
        int a = t + i * 1024;
        val[i] = (a < A_TOT);
        u[i] = val[i] ? __float_as_uint(max_s[b * A_TOT + a]) : 0u;
    }

    if (t == 0) { s_prefix = 0; s_k = MAX_DET; s_nHigh = 0; s_nTie = 0; s_cnt = 0; }

    for (int pass = 0; pass < 4; ++pass) {
#pragma unroll
        for (int j = 0; j < 4; ++j) hist[t + j * 1024] = 0;
        if (t == 0) s_selD = 0;
        __syncthreads();

        unsigned pre = s_prefix;
        int k = s_k;
        int shHi = 32 - 8 * pass;
        int shD = 24 - 8 * pass;
#pragma unroll
        for (int i = 0; i < 9; ++i) {
            if (val[i]) {
                bool cand = (pass == 0) ? true : ((u[i] >> shHi) == pre);
                if (cand)
                    atomicAdd(&hist[(wv << 8) + ((u[i] >> shD) & 0xFF)], 1u);
            }
        }
        __syncthreads();

        if (t < 256) {
            unsigned s = 0;
#pragma unroll
            for (int w = 0; w < 16; ++w) s += hist[(w << 8) + t];
            suffix[t] = s;
        }
        __syncthreads();
        for (int off = 1; off < 256; off <<= 1) {
            unsigned v = 0;
            if (t < 256) v = suffix[t] + ((t + off < 256) ? suffix[t + off] : 0u);
            __syncthreads();
            if (t < 256) suffix[t] = v;
            __syncthreads();
        }
        if (t < 256 && suffix[t] >= (unsigned)k) atomicMax(&s_selD, t);
        __syncthreads();
        if (t == 0) {
            int d = s_selD;
            s_k = k - ((d < 255) ? (int)suffix[d + 1] : 0);
            s_prefix = (pre << 8) | (unsigned)d;
        }
        __syncthreads();
    }

    unsigned cut = s_prefix;
    int r = s_k;

#pragma unroll
    for (int i = 0; i < 9; ++i) {
        if (val[i]) {
            int a = t + i * 1024;
            if (u[i] > cut) {
                int p = atomicAdd(&s_nHigh, 1);
                highKeys[p] = mk_key(u[i], a);
            } else if (u[i] == cut) {
                int p = atomicAdd(&s_nTie, 1);
                tieIdx[p] = a;
            }
        }
    }
    __syncthreads();
    int m = s_nHigh;
    int nt = s_nTie;

    if (t < 128) finalKeys[t] = 0ull;
    __syncthreads();
    if (t < m) finalKeys[t] = highKeys[t];

    if (nt == r) {
        if (t < nt) finalKeys[m + t] = mk_key(cut, tieIdx[t]);
        __syncthreads();
    } else {
        __syncthreads();
        for (int j = 0; j < r; ++j) {
            int mn = 0x7FFFFFFF;
            for (int p = t; p < nt; p += 1024) mn = min(mn, tieIdx[p]);
            for (int off = 32; off > 0; off >>= 1) mn = min(mn, __shfl_down(mn, off, 64));
            if ((t & 63) == 0) wmin[wv] = mn;
            __syncthreads();
            if (t == 0) {
                int v = wmin[0];
#pragma unroll
                for (int w = 1; w < 16; ++w) v = min(v, wmin[w]);
                s_bcast = v;
                finalKeys[m + j] = mk_key(cut, v);
            }
            __syncthreads();
            int v = s_bcast;
            for (int p = t; p < nt; p += 1024)
                if (tieIdx[p] == v) tieIdx[p] = 0x7FFFFFFF;
            __syncthreads();
        }
    }

    for (int ksz = 2; ksz <= 128; ksz <<= 1) {
        for (int j = ksz >> 1; j > 0; j >>= 1) {
            if (t < 128) {
                int ixj = t ^ j;
                if (ixj > t) {
                    bool desc = ((t & ksz) == 0);
                    unsigned long long x = finalKeys[t], y = finalKeys[ixj];
                    bool sw = desc ? (x < y) : (x > y);
                    if (sw) { finalKeys[t] = y; finalKeys[ixj] = x; }
                }
            }
            __syncthreads();
        }
    }

    if (t < MAX_DET) {
        unsigned long long kk = finalKeys[t];
        float sc = __uint_as_float((unsigned)(kk >> 32));
        int a = 0x7FFFFFFF - (int)(kk & 0xFFFFFFFFull);
        out[OUT_SCORE + b * MAX_DET + t] = sc;
        out[OUT_CLASS + b * MAX_DET + t] = (float)cls_id[b * A_TOT + a];
        top_idx[b * MAX_DET + t] = a;
        if (sc > 0.25f) atomicAdd(&s_cnt, 1);
    }
    __syncthreads();
    if (t == 0) out[OUT_NUM + b] = (float)s_cnt;
}

// -------- Kernel 3: decode box + kpts for selected anchors only --------
__global__ __launch_bounds__(128) void decode_kernel(
    const float* __restrict__ x0, const float* __restrict__ x1, const float* __restrict__ x2,
    const float* __restrict__ w2_0, const float* __restrict__ b2_0,
    const float* __restrict__ w2_1, const float* __restrict__ b2_1,
    const float* __restrict__ w2_2, const float* __restrict__ b2_2,
    const float* __restrict__ w4_0, const float* __restrict__ b4_0,
    const float* __restrict__ w4_1, const float* __restrict__ b4_1,
    const float* __restrict__ w4_2, const float* __restrict__ b4_2,
    const int* __restrict__ top_idx,
    float* __restrict__ out)
{
    int b = blockIdx.y;
    int k = blockIdx.x;
    int a = top_idx[b * MAX_DET + k];

    const float* x; const float* w2; const float* bb2; const float* w4; const float* bb4;
    int C, A, W, a_local; float stride;
    if (a < 6400)      { x = x0; C = 128; A = 6400; W = 80; stride = 8.0f;  a_local = a;        w2 = w2_0; bb2 = b2_0; w4 = w4_0; bb4 = b4_0; }
    else if (a < 8000) { x = x1; C = 256; A = 1600; W = 40; stride = 16.0f; a_local = a - 6400; w2 = w2_1; bb2 = b2_1; w4 = w4_1; bb4 = b4_1; }
    else               { x = x2; C = 512; A = 400;  W = 20; stride = 32.0f; a_local = a - 8000; w2 = w2_2; bb2 = b2_2; w4 = w4_2; bb4 = b4_2; }

    __shared__ float fs[512];
    __shared__ float logits[64];
    __shared__ float kraw[NK];
    __shared__ float dist[4];

    int t = threadIdx.x;
    for (int c = t; c < C; c += 128)
        fs[c] = x[((long)b * C + c) * A + a_local];
    __syncthreads();

    if (t < 64 + NK) {
        const float* wrow; float acc;
        if (t < 64) { wrow = w2 + t * C; acc = bb2[t]; }
        else        { wrow = w4 + (t - 64) * C; acc = bb4[t - 64]; }
#pragma unroll 4
        for (int c = 0; c < C; c += 8) {
            float4 wa = *(const float4*)(wrow + c);
            float4 wb = *(const float4*)(wrow + c + 4);
            float4 fa = *(const float4*)&fs[c];
            float4 fb = *(const float4*)&fs[c + 4];
            acc = fmaf(wa.x, fa.x, acc);
            acc = fmaf(wa.y, fa.y, acc);
            acc = fmaf(wa.z, fa.z, acc);
            acc = fmaf(wa.w, fa.w, acc);
            acc = fmaf(wb.x, fb.x, acc);
            acc = fmaf(wb.y, fb.y, acc);
            acc = fmaf(wb.z, fb.z, acc);
            acc = fmaf(wb.w, fb.w, acc);
        }
        if (t < 64) logits[t] = acc;
        else        kraw[t - 64] = acc;
    }
    __syncthreads();

    if (t < 4) {
        float mx = logits[t * 16];
#pragma unroll
        for (int r = 1; r < 16; ++r) mx = fmaxf(mx, logits[t * 16 + r]);
        float se = 0.0f, sw = 0.0f;
#pragma unroll
        for (int r = 0; r < 16; ++r) {
            float e = expf(logits[t * 16 + r] - mx);
            se += e; sw += e * (float)r;
        }
        dist[t] = sw / se;
    }
    __syncthreads();

    float ax = (float)(a_local % W) + 0.5f;
    float ay = (float)(a_local / W) + 0.5f;

    if (t == 0) {
        float x1c = ax - dist[0], y1c = ay - dist[1];
        float x2c = ax + dist[2], y2c = ay + dist[3];
        float* ob = out + OUT_BOX + ((long)b * MAX_DET + k) * 4;
        ob[0] = (x1c + x2c) * 0.5f * stride;
        ob[1] = (y1c + y2c) * 0.5f * stride;
        ob[2] = (x2c - x1c) * stride;
        ob[3] = (y2c - y1c) * stride;
    }
    if (t < 17) {
        float vx = kraw[t * 3], vy = kraw[t * 3 + 1], vv = kraw[t * 3 + 2];
        float gx = ax - 0.5f, gy = ay - 0.5f;
        float* ok = out + OUT_KPT + (((long)b * MAX_DET + k) * 17 + t) * 3;
        ok[0] = (vx * 2.0f + gx) * stride;
        ok[1] = (vy * 2.0f + gy) * stride;
        ok[2] = 1.0f / (1.0f + expf(-vv));
    }
}

extern "C" void kernel_launch(void* const* d_in, const int* in_sizes, int n_in,
                              void* d_out, int out_size, void* d_ws, size_t ws_size,
                              hipStream_t stream) {
    const float* x0 = (const float*)d_in[0];
    const float* x1 = (const float*)d_in[1];
    const float* x2 = (const float*)d_in[2];
    const float* w2[3] = {(const float*)d_in[3], (const float*)d_in[5], (const float*)d_in[7]};
    const float* b2[3] = {(const float*)d_in[4], (const float*)d_in[6], (const float*)d_in[8]};
    const float* w3[3] = {(const float*)d_in[9], (const float*)d_in[11], (const float*)d_in[13]};
    const float* b3[3] = {(const float*)d_in[10], (const float*)d_in[12], (const float*)d_in[14]};
    const float* w4[3] = {(const float*)d_in[15], (const float*)d_in[17], (const float*)d_in[19]};
    const float* b4[3] = {(const float*)d_in[16], (const float*)d_in[18], (const float*)d_in[20]};

    float* out = (float*)d_out;

    float* ws_maxs = (float*)d_ws;                    // [16][8400]
    int* ws_cls = (int*)(ws_maxs + BS * A_TOT);       // [16][8400]
    int* ws_top = (int*)(ws_cls + BS * A_TOT);        // [16][100]

    // equal-work fused scores: 112 (L2) + 208 (L1) + 400 (L0) = 720 blocks
    scores_fused<<<dim3(720), 256, 0, stream>>>(
        x0, x1, x2, w3[0], w3[1], w3[2], b3[0], b3[1], b3[2], ws_maxs, ws_cls);
    topk_kernel<<<dim3(BS), 1024, 0, stream>>>(ws_maxs, ws_cls, out, ws_top);
    decode_kernel<<<dim3(MAX_DET, BS), 128, 0, stream>>>(
        x0, x1, x2,
        w2[0], b2[0], w2[1], b2[1], w2[2], b2[2],
        w4[0], b4[0], w4[1], b4[1], w4[2], b4[2],
        ws_top, out);
}